// Round 16
// baseline (454.997 us; speedup 1.0000x reference)
//
#include <hip/hip_runtime.h>
#include <cmath>
#include <complex>
#include <cstdint>
#include <cstdio>
#include <cstring>
#include <mutex>
#include <string>
#include <utility>
#include <vector>
#include <dlfcn.h>

#define NND 32768
#define DDIM 1152
#define HDIM 384

typedef __bf16 bf16;
typedef __attribute__((ext_vector_type(8))) __bf16 bf16x8;
typedef __attribute__((ext_vector_type(4))) float f32x4;

// ===================== host: Wigner 3j generation (fallback path) =====================
namespace w3jgen {
using cd = std::complex<double>;

static void real_gens(int l, std::vector<double>* R) {
  const int d = 2 * l + 1;
  std::vector<cd> Lp(d * d), Lm(d * d);
  for (int i = 0; i + 1 < d; ++i) {
    double m = double(i - l);
    Lp[(i + 1) * d + i] = cd(std::sqrt(double(l) * (l + 1) - m * (m + 1)), 0.0);
  }
  for (int i = 0; i < d; ++i)
    for (int j = 0; j < d; ++j) Lm[i * d + j] = std::conj(Lp[j * d + i]);
  std::vector<cd> X[3];
  for (int a = 0; a < 3; ++a) X[a].assign(d * d, cd(0, 0));
  for (int i = 0; i < d * d; ++i) {
    X[0][i] = (Lp[i] + Lm[i]) * 0.5;
    X[1][i] = (Lp[i] - Lm[i]) / cd(0.0, 2.0);
  }
  for (int i = 0; i < d; ++i) X[2][i * d + i] = cd(double(i - l), 0.0);
  std::vector<cd> U(d * d, cd(0, 0));
  const double s2 = std::sqrt(2.0);
  for (int m = -l; m <= l; ++m) {
    int i = m + l;
    double sgn = (std::abs(m) % 2) ? -1.0 : 1.0;
    if (m < 0) {
      U[i * d + (l + m)] = cd(0.0, 1.0 / s2);
      U[i * d + (l - m)] = cd(0.0, -sgn / s2);
    } else if (m == 0) {
      U[i * d + l] = cd(1.0, 0.0);
    } else {
      U[i * d + (l - m)] = cd(1.0 / s2, 0.0);
      U[i * d + (l + m)] = cd(sgn / s2, 0.0);
    }
  }
  for (int a = 0; a < 3; ++a) {
    std::vector<cd> T(d * d, cd(0, 0)), T2(d * d, cd(0, 0));
    for (int i = 0; i < d; ++i)
      for (int k = 0; k < d; ++k) {
        cd u = U[i * d + k];
        if (u == cd(0, 0)) continue;
        for (int j = 0; j < d; ++j) T[i * d + j] += u * (cd(0, -1) * X[a][k * d + j]);
      }
    for (int i = 0; i < d; ++i)
      for (int k = 0; k < d; ++k) {
        cd t = T[i * d + k];
        if (t == cd(0, 0)) continue;
        for (int j = 0; j < d; ++j) T2[i * d + j] += t * std::conj(U[j * d + k]);
      }
    R[a].resize(d * d);
    for (int i = 0; i < d * d; ++i) R[a][i] = T2[i].real();
  }
}

static void wigner3j(int l1, int l2, int l3, float* out) {
  std::vector<double> X1[3], X2[3], X3[3];
  real_gens(l1, X1);
  real_gens(l2, X2);
  real_gens(l3, X3);
  const int d1 = 2 * l1 + 1, d2 = 2 * l2 + 1, d3 = 2 * l3 + 1;
  const int K = d1 * d2 * d3;
  std::vector<double> M((size_t)3 * K * K, 0.0);
  for (int a = 0; a < 3; ++a) {
    double* Ma = &M[(size_t)a * K * K];
    for (int i = 0; i < d1; ++i)
      for (int j = 0; j < d1; ++j) {
        double v = X1[a][i * d1 + j];
        if (v == 0.0) continue;
        for (int k = 0; k < d2; ++k)
          for (int m = 0; m < d3; ++m)
            Ma[(size_t)((i * d2 + k) * d3 + m) * K + ((j * d2 + k) * d3 + m)] += v;
      }
    for (int k = 0; k < d2; ++k)
      for (int l = 0; l < d2; ++l) {
        double v = X2[a][k * d2 + l];
        if (v == 0.0) continue;
        for (int i = 0; i < d1; ++i)
          for (int m = 0; m < d3; ++m)
            Ma[(size_t)((i * d2 + k) * d3 + m) * K + ((i * d2 + l) * d3 + m)] += v;
      }
    for (int m = 0; m < d3; ++m)
      for (int n = 0; n < d3; ++n) {
        double v = X3[a][m * d3 + n];
        if (v == 0.0) continue;
        for (int i = 0; i < d1; ++i)
          for (int k = 0; k < d2; ++k)
            Ma[(size_t)((i * d2 + k) * d3 + m) * K + ((i * d2 + k) * d3 + n)] += v;
      }
  }
  const int rows = 3 * K;
  std::vector<int> pivrow(K, -1);
  int r = 0;
  for (int c = 0; c < K && r < rows; ++c) {
    int p = -1;
    double best = 1e-9;
    for (int q = r; q < rows; ++q) {
      double v = std::fabs(M[(size_t)q * K + c]);
      if (v > best) { best = v; p = q; }
    }
    if (p < 0) continue;
    if (p != r)
      for (int j = 0; j < K; ++j) std::swap(M[(size_t)p * K + j], M[(size_t)r * K + j]);
    double inv = 1.0 / M[(size_t)r * K + c];
    for (int j = 0; j < K; ++j) M[(size_t)r * K + j] *= inv;
    for (int q = 0; q < rows; ++q) {
      if (q == r) continue;
      double f = M[(size_t)q * K + c];
      if (f == 0.0) continue;
      for (int j = 0; j < K; ++j) M[(size_t)q * K + j] -= f * M[(size_t)r * K + j];
    }
    pivrow[c] = r;
    ++r;
  }
  int cf = -1;
  for (int c = 0; c < K; ++c)
    if (pivrow[c] < 0) { cf = c; break; }
  std::vector<double> v(K, 0.0);
  v[cf] = 1.0;
  for (int c = 0; c < K; ++c)
    if (pivrow[c] >= 0) v[c] = -M[(size_t)pivrow[c] * K + cf];
  double nrm = 0.0;
  for (double x : v) nrm += x * x;
  nrm = std::sqrt(nrm);
  for (double& x : v) x /= nrm;
  double mx = 0.0;
  for (double x : v) mx = std::max(mx, std::fabs(x));
  int idx = 0;
  for (int i = 0; i < K; ++i)
    if (std::fabs(v[i]) > mx - 1e-9) { idx = i; break; }
  double s = (v[idx] < 0 ? -1.0 : 1.0);
  for (int i = 0; i < K; ++i) out[i] = (float)(v[i] * s);
}
}  // namespace w3jgen

struct W3JPack { float v[615]; };
static W3JPack g_w3j;
static const bool g_w3j_ready = [] {
  const int L1[15] = {0, 0, 0, 1, 1, 1, 1, 1, 1, 2, 2, 2, 2, 2, 2};
  const int L2[15] = {0, 1, 2, 0, 1, 1, 1, 2, 2, 0, 1, 1, 2, 2, 2};
  const int LO[15] = {0, 1, 2, 1, 0, 1, 2, 1, 2, 2, 1, 2, 0, 1, 2};
  const int OFF[15] = {0, 1, 10, 35, 44, 53, 80, 125, 170, 245, 270, 315, 390, 415, 490};
  for (int k = 0; k < 15; ++k)
    w3jgen::wigner3j(L1[k], L2[k], LO[k], g_w3j.v + OFF[k]);
  return true;
}();

// ===================== sparse W3J structure =====================
struct SpEnt { signed char ia, ib, c; };
struct SpIns { signed char l1, l2, lo; short off; signed char kidx, n; SpEnt e[25]; };
constexpr SpIns SPT[15] = {
  {0,0,0,   0, 0, 1, {{0,0,0}}},
  {0,1,1,   1, 1, 3, {{0,0,0},{0,1,1},{0,2,2}}},
  {0,2,2,  10, 2, 5, {{0,0,0},{0,1,1},{0,2,2},{0,3,3},{0,4,4}}},
  {1,0,1,  35, 3, 3, {{0,0,0},{1,0,1},{2,0,2}}},
  {1,1,0,  44, 4, 3, {{0,0,0},{1,1,0},{2,2,0}}},
  {1,1,1,  53, 5, 6, {{0,1,2},{0,2,1},{1,0,2},{1,2,0},{2,0,1},{2,1,0}}},
  {1,1,2,  80, 6,11, {{0,0,2},{0,0,4},{1,1,2},{2,2,2},{2,2,4},{0,1,1},{1,0,1},{0,2,0},{2,0,0},{1,2,3},{2,1,3}}},
  {1,2,1, 125, 7,11, {{0,2,0},{0,4,0},{1,2,1},{2,2,2},{2,4,2},{0,1,1},{1,1,0},{0,0,2},{2,0,0},{1,3,2},{2,3,1}}},
  {1,2,2, 170, 8,16, {{0,0,1},{0,1,0},{0,2,3},{0,3,2},{0,3,4},{0,4,3},{1,0,4},{1,4,0},{1,1,3},{1,3,1},{2,1,2},{2,2,1},{2,1,4},{2,4,1},{2,0,3},{2,3,0}}},
  {2,0,2, 245, 9, 5, {{0,0,0},{1,0,1},{2,0,2},{3,0,3},{4,0,4}}},
  {2,1,1, 270,10,11, {{2,0,0},{4,0,0},{2,1,1},{2,2,2},{4,2,2},{1,0,1},{1,1,0},{0,0,2},{0,2,0},{3,1,2},{3,2,1}}},
  {2,1,2, 315,11,16, {{0,0,1},{1,0,0},{2,0,3},{3,0,2},{3,0,4},{4,0,3},{0,1,4},{4,1,0},{1,1,3},{3,1,1},{1,2,2},{2,2,1},{1,2,4},{4,2,1},{0,2,3},{3,2,0}}},
  {2,2,0, 390,12, 5, {{0,0,0},{1,1,0},{2,2,0},{3,3,0},{4,4,0}}},
  {2,2,1, 415,13,16, {{0,1,0},{1,0,0},{2,3,0},{3,2,0},{3,4,0},{4,3,0},{0,4,1},{4,0,1},{1,3,1},{3,1,1},{1,2,2},{2,1,2},{1,4,2},{4,1,2},{0,3,2},{3,0,2}}},
  {2,2,2, 490,14,25, {{2,2,2},{0,0,2},{0,2,0},{2,0,0},{1,1,2},{1,2,1},{2,1,1},{3,3,2},{3,2,3},{2,3,3},{4,4,2},{4,2,4},{2,4,4},{1,1,4},{1,4,1},{4,1,1},{3,3,4},{3,4,3},{4,3,3},{0,1,3},{0,3,1},{1,0,3},{1,3,0},{3,0,1},{3,1,0}}},
};

static bool validate_sparse() {
  bool mark[615] = {};
  for (int k = 0; k < 15; ++k) {
    const SpIns& S = SPT[k];
    const int d2 = 2 * S.l2 + 1, d3 = 2 * S.lo + 1;
    for (int e = 0; e < S.n; ++e) {
      int flat = S.off + (S.e[e].ia * d2 + S.e[e].ib) * d3 + S.e[e].c;
      if (flat < 0 || flat >= 615) return false;
      mark[flat] = true;
    }
  }
  for (int i = 0; i < 615; ++i)
    if (!mark[i] && std::fabs(g_w3j.v[i]) > 1e-4f) return false;
  return true;
}
static bool g_use_sparse = false;

// ===================== host: bit-exact W3J via in-process numpy =====================
static const char* kPySrc = R"PY(
def _sl7791_w3j(addr):
    import numpy as np, ctypes
    def _su2_gen(l):
        m = np.arange(-l, l + 1)
        Lz = np.diag(m).astype(complex)
        Lp = np.zeros((2 * l + 1, 2 * l + 1), complex)
        for i in range(2 * l):
            Lp[i + 1, i] = np.sqrt(l * (l + 1) - m[i] * (m[i] + 1))
        Lm = Lp.conj().T
        return ((Lp + Lm) / 2, (Lp - Lm) / 2j, Lz)
    def _c2r(l):
        d = 2 * l + 1
        U = np.zeros((d, d), complex)
        s2 = np.sqrt(2.0)
        for m in range(-l, l + 1):
            i = m + l
            if m < 0:
                U[i, l + m] = 1j / s2
                U[i, l - m] = -1j * (-1) ** m / s2
            elif m == 0:
                U[i, l] = 1.0
            else:
                U[i, l - m] = 1.0 / s2
                U[i, l + m] = (-1) ** m / s2
        return U
    def _real_gens(l):
        U = _c2r(l)
        return [np.real(U @ (-1j * L) @ U.conj().T) for L in _su2_gen(l)]
    def _w3j(l1, l2, l3):
        X1, X2, X3 = (_real_gens(l1), _real_gens(l2), _real_gens(l3))
        d1, d2, d3 = (2 * l1 + 1, 2 * l2 + 1, 2 * l3 + 1)
        I1, I2, I3 = (np.eye(d1), np.eye(d2), np.eye(d3))
        blocks = []
        for a in range(3):
            T = np.einsum('ij,kl,mn->ikmjln', X1[a], I2, I3) + np.einsum('ij,kl,mn->ikmjln', I1, X2[a], I3) + np.einsum('ij,kl,mn->ikmjln', I1, I2, X3[a])
            blocks.append(T.reshape(d1 * d2 * d3, d1 * d2 * d3))
        M = np.concatenate(blocks, 0)
        _, _, vh = np.linalg.svd(M)
        C = vh[-1].reshape(d1, d2, d3)
        if C.flat[np.argmax(np.abs(C))] < 0:
            C = -C
        return (C / np.linalg.norm(C)).astype(np.float32)
    INS = [(0,0,0),(0,1,1),(0,2,2),(1,0,1),(1,1,0),(1,1,1),(1,1,2),(1,2,1),(1,2,2),(2,0,2),(2,1,1),(2,1,2),(2,2,0),(2,2,1),(2,2,2)]
    flat = np.ascontiguousarray(np.concatenate([_w3j(*i).ravel() for i in INS]).astype(np.float32))
    ctypes.memmove(addr, flat.ctypes.data, flat.nbytes)
)PY";

static bool python_w3j() {
  typedef int (*PyIsInit_t)();
  typedef int (*PyGILEnsure_t)();
  typedef void (*PyGILRelease_t)(int);
  typedef int (*PyRunStr_t)(const char*);
  void* h = nullptr;  // RTLD_DEFAULT
  PyIsInit_t is_init = (PyIsInit_t)dlsym(h, "Py_IsInitialized");
  PyGILEnsure_t gil_ens = (PyGILEnsure_t)dlsym(h, "PyGILState_Ensure");
  PyGILRelease_t gil_rel = (PyGILRelease_t)dlsym(h, "PyGILState_Release");
  PyRunStr_t run = (PyRunStr_t)dlsym(h, "PyRun_SimpleString");
  if (!is_init || !gil_ens || !gil_rel || !run) return false;
  if (!is_init()) return false;
  std::string script(kPySrc);
  script += "\n_sl7791_w3j(" + std::to_string((unsigned long long)(uintptr_t)g_w3j.v) +
            ")\ndel _sl7791_w3j\n";
  int st = gil_ens();
  int rc = run(script.c_str());
  gil_rel(st);
  return rc == 0;
}

static std::once_flag g_w3j_once;
static void ensure_w3j() {
  std::call_once(g_w3j_once, [] {
    W3JPack backup = g_w3j;
    if (python_w3j()) {
      if (!(std::fabs(std::fabs(g_w3j.v[0]) - 1.0f) < 1e-3f)) g_w3j = backup;
    }
    g_use_sparse = validate_sparse();
  });
}

// ===================== device kernels =====================

struct WPtrs {
  const float* gw[6];
  const float* ow[3];
};
#define WB_O3_OFF 884736  // 6*147456

// ---- fused prologue: f0/xT build (blocks 0..16383) + weight prep (blocks 16384..21567) ----
__global__ __launch_bounds__(256) void prep_f0x_kernel(WPtrs p, bf16* __restrict__ wb,
                                                       const float* __restrict__ x,
                                                       bf16* __restrict__ f0,
                                                       bf16* __restrict__ xT) {
  const int bid = blockIdx.x;
  if (bid < 16384) {
    const int idx = bid * 256 + threadIdx.x;
    const int n = idx >> 7, u = idx & 127;
    const float* xr = x + (size_t)n * DDIM;
    const float x0 = xr[u];
    float v1[3], v2[5];
    float s1 = 0.f, s2 = 0.f;
#pragma unroll
    for (int i = 0; i < 3; ++i) { v1[i] = xr[128 + u * 3 + i]; s1 += v1[i] * v1[i]; }
#pragma unroll
    for (int i = 0; i < 5; ++i) { v2[i] = xr[512 + u * 5 + i]; s2 += v2[i] * v2[i]; }
    bf16* f = f0 + (size_t)n * HDIM;
    f[u] = (bf16)x0;
    f[128 + u] = (bf16)sqrtf(s1);
    f[256 + u] = (bf16)sqrtf(s2);
    bf16* xt = xT + (size_t)n * 1024;
#pragma unroll
    for (int i = 0; i < 3; ++i) xt[i * 128 + u] = (bf16)v1[i];
#pragma unroll
    for (int i = 0; i < 5; ++i) xt[(3 + i) * 128 + u] = (bf16)v2[i];
  } else {
    const int id = bid - 16384;
    const int y = id / 576;
    const int e = (id - y * 576) * 256 + threadIdx.x;
    if (y < 6) {
      wb[(size_t)y * 147456 + e] = (bf16)p.gw[y][e];
    } else {
      if (e >= 49152) return;
      const int j = y - 6;
      const int l = e >> 14, vu = e & 16383, v = vu >> 7, u = vu & 127;
      wb[WB_O3_OFF + (size_t)j * 49152 + l * 16384 + v * 128 + u] =
          (bf16)p.ow[j][l * 16384 + u * 128 + v];
    }
  }
}

// ---- gate GEMM (bf16 MFMA, 64x128 tile; optional dual set select on blockIdx.y) ----
struct DualPtrs { const void* A2; const bf16* W2; const float* bias2; void* D2; };

template <int EPI, int CB, bool DUAL>
__global__ __launch_bounds__(256) void mm_kernel(const void* Asrc, const bf16* Wt,
                                                 const float* bias, void* Dst, DualPtrs dp) {
  __shared__ alignas(16) bf16 As[64][72];
  __shared__ alignas(16) bf16 Bs[128][72];
  int by = blockIdx.y;
  if (DUAL && by >= CB) {
    by -= CB;
    Asrc = dp.A2; Wt = dp.W2; bias = dp.bias2; Dst = dp.D2;
  }
  const int t = threadIdx.x;
  const int row0 = blockIdx.x * 64;
  const int col0 = by * 128;
  const int wave = t >> 6, lane = t & 63;
  const int wm = wave >> 1, wn = wave & 1;
  const int lr = lane & 15, lk = (lane >> 4) * 8;
  f32x4 acc[2][4] = {};
  const int ra = t >> 2, cseg = (t & 3) * 16;
  const int rb = t >> 1, csegB = (t & 1) * 32;

  for (int k0 = 0; k0 < 384; k0 += 64) {
    const bf16* s = (const bf16*)Asrc + (size_t)(row0 + ra) * HDIM + k0 + cseg;
    bf16x8 a0 = *(const bf16x8*)s, a1 = *(const bf16x8*)(s + 8);
    const bf16* wsrc = Wt + (size_t)(col0 + rb) * HDIM + k0 + csegB;
    bf16x8 w0 = *(const bf16x8*)wsrc, w1 = *(const bf16x8*)(wsrc + 8);
    bf16x8 w2 = *(const bf16x8*)(wsrc + 16), w3 = *(const bf16x8*)(wsrc + 24);
    __syncthreads();
    *(bf16x8*)&As[ra][cseg] = a0; *(bf16x8*)&As[ra][cseg + 8] = a1;
    *(bf16x8*)&Bs[rb][csegB] = w0; *(bf16x8*)&Bs[rb][csegB + 8] = w1;
    *(bf16x8*)&Bs[rb][csegB + 16] = w2; *(bf16x8*)&Bs[rb][csegB + 24] = w3;
    __syncthreads();
#pragma unroll
    for (int ks = 0; ks < 2; ++ks) {
      bf16x8 af[2], bfv[4];
#pragma unroll
      for (int f = 0; f < 2; ++f)
        af[f] = *(const bf16x8*)&As[wm * 32 + f * 16 + lr][ks * 32 + lk];
#pragma unroll
      for (int f = 0; f < 4; ++f)
        bfv[f] = *(const bf16x8*)&Bs[wn * 64 + f * 16 + lr][ks * 32 + lk];
#pragma unroll
      for (int fm = 0; fm < 2; ++fm)
#pragma unroll
        for (int fn = 0; fn < 4; ++fn)
          acc[fm][fn] = __builtin_amdgcn_mfma_f32_16x16x32_bf16(af[fm], bfv[fn], acc[fm][fn], 0, 0, 0);
    }
  }

#pragma unroll
  for (int fm = 0; fm < 2; ++fm) {
#pragma unroll
    for (int fn = 0; fn < 4; ++fn) {
      const int col = col0 + wn * 64 + fn * 16 + lr;
#pragma unroll
      for (int r = 0; r < 4; ++r) {
        const int rowo = row0 + wm * 32 + fm * 16 + (lane >> 4) * 4 + r;
        float v = acc[fm][fn][r] + bias[col];
        if (EPI == 0) v = v / (1.f + __expf(-v));
        ((bf16*)Dst)[(size_t)rowo * HDIM + col] = (bf16)v;
      }
    }
  }
}

// ---- o3 GEMM body, 64 rows x 128 cols (used by o3_first) ----
template <int TL>
__device__ __forceinline__ void o3_body128(int row0, const bf16* __restrict__ A,
                                           const bf16* __restrict__ G,
                                           const bf16* __restrict__ Wt,
                                           const float* __restrict__ bias,
                                           void* __restrict__ Dst, char* smraw) {
  bf16 (*As)[72] = reinterpret_cast<bf16(*)[72]>(smraw);
  bf16 (*Bs)[72] = reinterpret_cast<bf16(*)[72]>(smraw + 64 * 72 * 2);
  const int t = threadIdx.x;
  const int wave = t >> 6, lane = t & 63;
  const int wm = wave >> 1, wn = wave & 1;
  const int lr = lane & 15, lk = (lane >> 4) * 8;
  f32x4 acc[2][4] = {};
  const int ra = t >> 2, cseg = (t & 3) * 16;
  const int rb = t >> 1, csegB = (t & 1) * 32;
  constexpr int goff = (TL == 3) ? 128 : 256;
  constexpr int coff = (TL == 3) ? 1 : ((TL == 5) ? 4 : 0);
  const int rowg = row0 + ra;
  const int n_a = rowg / TL, i_a = rowg % TL;

  for (int k0 = 0; k0 < 128; k0 += 64) {
    bf16 av[16];
    if (TL == 1) {
      const bf16* s = A + (size_t)rowg * HDIM + k0 + cseg;
      *(bf16x8*)&av[0] = *(const bf16x8*)s;
      *(bf16x8*)&av[8] = *(const bf16x8*)(s + 8);
    } else {
      const bf16* xs = A + (size_t)n_a * 1024 + (coff - 1 + i_a) * 128 + k0 + cseg;
      const bf16* gs = G + (size_t)n_a * HDIM + goff + k0 + cseg;
      bf16 xv[16], gv[16];
      *(bf16x8*)&xv[0] = *(const bf16x8*)xs;
      *(bf16x8*)&xv[8] = *(const bf16x8*)(xs + 8);
      *(bf16x8*)&gv[0] = *(const bf16x8*)gs;
      *(bf16x8*)&gv[8] = *(const bf16x8*)(gs + 8);
#pragma unroll
      for (int e = 0; e < 16; ++e) av[e] = (bf16)((float)xv[e] * (float)gv[e]);
    }
    const bf16* wsrc = Wt + (size_t)rb * 128 + k0 + csegB;
    bf16x8 w0 = *(const bf16x8*)wsrc, w1 = *(const bf16x8*)(wsrc + 8);
    bf16x8 w2 = *(const bf16x8*)(wsrc + 16), w3 = *(const bf16x8*)(wsrc + 24);
    __syncthreads();
    *(bf16x8*)&As[ra][cseg] = *(bf16x8*)&av[0];
    *(bf16x8*)&As[ra][cseg + 8] = *(bf16x8*)&av[8];
    *(bf16x8*)&Bs[rb][csegB] = w0; *(bf16x8*)&Bs[rb][csegB + 8] = w1;
    *(bf16x8*)&Bs[rb][csegB + 16] = w2; *(bf16x8*)&Bs[rb][csegB + 24] = w3;
    __syncthreads();
#pragma unroll
    for (int ks = 0; ks < 2; ++ks) {
      bf16x8 af[2], bfv[4];
#pragma unroll
      for (int f = 0; f < 2; ++f)
        af[f] = *(const bf16x8*)&As[wm * 32 + f * 16 + lr][ks * 32 + lk];
#pragma unroll
      for (int f = 0; f < 4; ++f)
        bfv[f] = *(const bf16x8*)&Bs[wn * 64 + f * 16 + lr][ks * 32 + lk];
#pragma unroll
      for (int fm = 0; fm < 2; ++fm)
#pragma unroll
        for (int fn = 0; fn < 4; ++fn)
          acc[fm][fn] = __builtin_amdgcn_mfma_f32_16x16x32_bf16(af[fm], bfv[fn], acc[fm][fn], 0, 0, 0);
    }
  }

  const float rs = 0.08838834764831843f;  // 1/sqrt(128)
#pragma unroll
  for (int fm = 0; fm < 2; ++fm) {
#pragma unroll
    for (int fn = 0; fn < 4; ++fn) {
      const int col = wn * 64 + fn * 16 + lr;
#pragma unroll
      for (int r = 0; r < 4; ++r) {
        const int rowo = row0 + wm * 32 + fm * 16 + (lane >> 4) * 4 + r;
        float v = acc[fm][fn][r] * rs;
        if (TL == 1) v += bias[col];
        const int n = rowo / TL, ii = rowo % TL;
        ((bf16*)Dst)[(size_t)n * DDIM + (coff + ii) * 128 + col] = (bf16)v;
      }
    }
  }
}

// ---- o3 GEMM body, 64 rows x 64 cols (used by o3_final; r8-proven) ----
template <int TL>
__device__ __forceinline__ void o3_body64(int row0, int col0, const bf16* __restrict__ A,
                                          const bf16* __restrict__ G,
                                          const bf16* __restrict__ Wt,
                                          const float* __restrict__ oldf,
                                          float* __restrict__ Dst, char* smraw) {
  bf16 (*As)[72] = reinterpret_cast<bf16(*)[72]>(smraw);
  bf16 (*Bs)[72] = reinterpret_cast<bf16(*)[72]>(smraw + 64 * 72 * 2);
  float (*Cs)[65] = reinterpret_cast<float(*)[65]>(smraw);
  const int t = threadIdx.x;
  const int wave = t >> 6, lane = t & 63;
  const int wm = wave >> 1, wn = wave & 1;
  const int lr = lane & 15, lk = (lane >> 4) * 8;
  f32x4 acc[2][2] = {};
  const int ra = t >> 2, cseg = (t & 3) * 16;
  constexpr int goff = (TL == 3) ? 128 : 256;
  constexpr int coff = (TL == 3) ? 1 : ((TL == 5) ? 4 : 0);
  constexpr int moff = (TL == 3) ? 128 : 512;
  const int rowg = row0 + ra;
  const int n_a = rowg / TL, i_a = rowg % TL;

  for (int k0 = 0; k0 < 128; k0 += 64) {
    bf16 av[16];
    if (TL == 1) {
      const bf16* s = A + (size_t)rowg * HDIM + k0 + cseg;
      *(bf16x8*)&av[0] = *(const bf16x8*)s;
      *(bf16x8*)&av[8] = *(const bf16x8*)(s + 8);
    } else {
      const bf16* xs = A + (size_t)n_a * 1024 + (coff - 1 + i_a) * 128 + k0 + cseg;
      const bf16* gs = G + (size_t)n_a * HDIM + goff + k0 + cseg;
      bf16 xv[16], gv[16];
      *(bf16x8*)&xv[0] = *(const bf16x8*)xs;
      *(bf16x8*)&xv[8] = *(const bf16x8*)(xs + 8);
      *(bf16x8*)&gv[0] = *(const bf16x8*)gs;
      *(bf16x8*)&gv[8] = *(const bf16x8*)(gs + 8);
#pragma unroll
      for (int e = 0; e < 16; ++e) av[e] = (bf16)((float)xv[e] * (float)gv[e]);
    }
    const bf16* wsrc = Wt + (size_t)(col0 + ra) * 128 + k0 + cseg;
    bf16x8 w0 = *(const bf16x8*)wsrc;
    bf16x8 w1 = *(const bf16x8*)(wsrc + 8);
    __syncthreads();
    *(bf16x8*)&As[ra][cseg] = *(bf16x8*)&av[0];
    *(bf16x8*)&As[ra][cseg + 8] = *(bf16x8*)&av[8];
    *(bf16x8*)&Bs[ra][cseg] = w0;
    *(bf16x8*)&Bs[ra][cseg + 8] = w1;
    __syncthreads();
#pragma unroll
    for (int ks = 0; ks < 2; ++ks) {
      bf16x8 af[2], bfv[2];
#pragma unroll
      for (int f = 0; f < 2; ++f) {
        af[f]  = *(const bf16x8*)&As[wm * 32 + f * 16 + lr][ks * 32 + lk];
        bfv[f] = *(const bf16x8*)&Bs[wn * 32 + f * 16 + lr][ks * 32 + lk];
      }
#pragma unroll
      for (int fm = 0; fm < 2; ++fm)
#pragma unroll
        for (int fn = 0; fn < 2; ++fn)
          acc[fm][fn] = __builtin_amdgcn_mfma_f32_16x16x32_bf16(af[fm], bfv[fn], acc[fm][fn], 0, 0, 0);
    }
  }

  const float rs = 0.08838834764831843f;  // 1/sqrt(128)

  if (TL != 1) {  // LDS transpose, merged f32 + oldf
    __syncthreads();
#pragma unroll
    for (int fm = 0; fm < 2; ++fm)
#pragma unroll
      for (int fn = 0; fn < 2; ++fn)
#pragma unroll
        for (int r = 0; r < 4; ++r)
          Cs[wm * 32 + fm * 16 + (lane >> 4) * 4 + r][wn * 32 + fn * 16 + lr] =
              acc[fm][fn][r] * rs;
    __syncthreads();
    const int n_first = row0 / TL;
    const int n_last = (row0 + 63) / TL;
    for (int n = n_first; n <= n_last; ++n) {
      const size_t obase = (size_t)n * DDIM + moff + (size_t)col0 * TL;
      for (int e = t; e < 64 * TL; e += 256) {
        const int cl = e / TL;
        const int i = e - cl * TL;
        const int trow = n * TL + i - row0;
        if ((unsigned)trow < 64u) {
          const size_t oidx = obase + e;
          Dst[oidx] = Cs[trow][cl] + oldf[oidx];
        }
      }
    }
    return;
  }

#pragma unroll
  for (int fm = 0; fm < 2; ++fm) {
#pragma unroll
    for (int fn = 0; fn < 2; ++fn) {
      const int col = col0 + wn * 32 + fn * 16 + lr;
#pragma unroll
      for (int r = 0; r < 4; ++r) {
        const int rowo = row0 + wm * 32 + fm * 16 + (lane >> 4) * 4 + r;
        const size_t oidx = (size_t)rowo * DDIM + col;
        Dst[oidx] = acc[fm][fn][r] * rs + oldf[oidx];
      }
    }
  }
}

// ---- combined first-stage o3 (l+r): 9216 blocks, 64x128 tiles (TL5 first) ----
// XCD-aware bijective swizzle: hardware round-robins blockIdx%8 across XCDs; the chunked
// remap gives each XCD a contiguous logical range so (l,r) set-pairs (which share xT rows)
// land on the same XCD's L2. 9216 % 8 == 0 -> exact.
struct O3First {
  const bf16* xT;
  const bf16* g[2];
  const bf16* w[2];
  const float* bias[2];
  bf16* dst[2];
};
__global__ __launch_bounds__(256) void o3_first_kernel(O3First a) {
  __shared__ alignas(16) char smraw[27648];
  const int id = (blockIdx.x & 7) * 1152 + (blockIdx.x >> 3);  // 9216/8 = 1152
  if (id < 5120) {
    const int set = id & 1, rt = id >> 1;
    o3_body128<5>(rt * 64, a.xT, a.g[set], a.w[set] + 32768, nullptr, a.dst[set], smraw);
  } else if (id < 8192) {
    const int tt = id - 5120;
    const int set = tt & 1, rt = tt >> 1;
    o3_body128<3>(rt * 64, a.xT, a.g[set], a.w[set] + 16384, nullptr, a.dst[set], smraw);
  } else {
    const int tt = id - 8192;
    const int set = tt & 1, rt = tt >> 1;
    o3_body128<1>(rt * 64, a.g[set], nullptr, a.w[set], a.bias[set], a.dst[set], smraw);
  }
}

// ---- combined final o3: 9216 blocks, 64x64 tiles (r8-proven) ----
// Same chunked swizzle: col-half pairs (2k, 2k+1) share identical xtp/g rows -> same XCD L2.
struct O3Final {
  const bf16* xtp;
  const bf16* g;
  const bf16* w;
  const float* oldf;
  float* out;
};
__global__ __launch_bounds__(256) void o3_final_kernel(O3Final a) {
  __shared__ alignas(16) char smraw[18432];
  const int id = (blockIdx.x & 7) * 1152 + (blockIdx.x >> 3);  // 9216/8 = 1152
  if (id < 1024) {
    const int col = id & 1, rt = id >> 1;
    o3_body64<1>(rt * 64, col * 64, a.g, nullptr, a.w, a.oldf, a.out, smraw);
  } else if (id < 4096) {
    const int tt = id - 1024;
    const int col = tt & 1, rt = tt >> 1;
    o3_body64<3>(rt * 64, col * 64, a.xtp, a.g, a.w + 16384, a.oldf, a.out, smraw);
  } else {
    const int tt = id - 4096;
    const int col = tt & 1, rt = tt >> 1;
    o3_body64<5>(rt * 64, col * 64, a.xtp, a.g, a.w + 32768, a.oldf, a.out, smraw);
  }
}

// ---- tensor product ----
__device__ __forceinline__ void tp_epilogue(float (&o)[9], int n, int u,
                                            bf16* __restrict__ xtp,
                                            bf16* __restrict__ f0) {
  const float s0 = 0.5773502691896258f;
  const float s1 = 0.7071067811865476f;
  const float s2 = 0.9128709291752769f;
  o[0] *= s0;
  o[1] *= s1; o[2] *= s1; o[3] *= s1;
  o[4] *= s2; o[5] *= s2; o[6] *= s2; o[7] *= s2; o[8] *= s2;
  const float n1 = sqrtf(o[1] * o[1] + o[2] * o[2] + o[3] * o[3]);
  const float n2 = sqrtf(o[4] * o[4] + o[5] * o[5] + o[6] * o[6] + o[7] * o[7] + o[8] * o[8]);
  bf16* f = f0 + (size_t)n * HDIM;
  f[u] = (bf16)o[0];
  f[128 + u] = (bf16)n1;
  f[256 + u] = (bf16)n2;
  bf16* op = xtp + (size_t)n * 1024 + u;
#pragma unroll
  for (int c = 1; c < 9; ++c) op[(c - 1) * 128] = (bf16)o[c];
}

template <int l1, int l2, int lo, int off, int kidx>
__device__ __forceinline__ void tp_one(const W3JPack& w3j, const float* __restrict__ tpw,
                                       int u, const float (&a)[9], const float (&b)[9],
                                       float (&o)[9]) {
  constexpr int d1 = 2 * l1 + 1, d2 = 2 * l2 + 1, d3 = 2 * lo + 1;
  constexpr int o1 = (l1 == 0) ? 0 : ((l1 == 1) ? 1 : 4);
  constexpr int o2 = (l2 == 0) ? 0 : ((l2 == 1) ? 1 : 4);
  constexpr int o3 = (lo == 0) ? 0 : ((lo == 1) ? 1 : 4);
  const float w = tpw[kidx * 128 + u];
  float ab[d1 * d2];
#pragma unroll
  for (int ia = 0; ia < d1; ++ia)
#pragma unroll
    for (int ib = 0; ib < d2; ++ib) ab[ia * d2 + ib] = a[o1 + ia] * b[o2 + ib];
#pragma unroll
  for (int c = 0; c < d3; ++c) {
    float p = 0.f;
#pragma unroll
    for (int e = 0; e < d1 * d2; ++e) p = fmaf(w3j.v[off + e * d3 + c], ab[e], p);
    o[o3 + c] = fmaf(w, p, o[o3 + c]);
  }
}

__global__ __launch_bounds__(256) void tp_dense_kernel(const bf16* __restrict__ xl,
                                                       const bf16* __restrict__ xr,
                                                       const float* __restrict__ tpw,
                                                       bf16* __restrict__ xtp,
                                                       bf16* __restrict__ f0,
                                                       const W3JPack w3j) {
  const int idx = blockIdx.x * 256 + threadIdx.x;
  const int n = idx >> 7, u = idx & 127;
  const bf16* ap = xl + (size_t)n * DDIM + u;
  const bf16* bp = xr + (size_t)n * DDIM + u;
  float a[9], b[9], o[9];
#pragma unroll
  for (int c = 0; c < 9; ++c) {
    a[c] = (float)ap[c * 128];
    b[c] = (float)bp[c * 128];
    o[c] = 0.f;
  }
  tp_one<0, 0, 0,   0,  0>(w3j, tpw, u, a, b, o);
  tp_one<0, 1, 1,   1,  1>(w3j, tpw, u, a, b, o);
  tp_one<0, 2, 2,  10,  2>(w3j, tpw, u, a, b, o);
  tp_one<1, 0, 1,  35,  3>(w3j, tpw, u, a, b, o);
  tp_one<1, 1, 0,  44,  4>(w3j, tpw, u, a, b, o);
  tp_one<1, 1, 1,  53,  5>(w3j, tpw, u, a, b, o);
  tp_one<1, 1, 2,  80,  6>(w3j, tpw, u, a, b, o);
  tp_one<1, 2, 1, 125,  7>(w3j, tpw, u, a, b, o);
  tp_one<1, 2, 2, 170,  8>(w3j, tpw, u, a, b, o);
  tp_one<2, 0, 2, 245,  9>(w3j, tpw, u, a, b, o);
  tp_one<2, 1, 1, 270, 10>(w3j, tpw, u, a, b, o);
  tp_one<2, 1, 2, 315, 11>(w3j, tpw, u, a, b, o);
  tp_one<2, 2, 0, 390, 12>(w3j, tpw, u, a, b, o);
  tp_one<2, 2, 1, 415, 13>(w3j, tpw, u, a, b, o);
  tp_one<2, 2, 2, 490, 14>(w3j, tpw, u, a, b, o);
  tp_epilogue(o, n, u, xtp, f0);
}

template <int K, int E>
__device__ __forceinline__ void tp_se(const W3JPack& w, const float (&a)[9],
                                      const float (&b)[9], float (&p)[5]) {
  constexpr SpIns S = SPT[K];
  constexpr int ia = S.e[E].ia, ib = S.e[E].ib, cc = S.e[E].c;
  constexpr int d2 = 2 * S.l2 + 1, d3 = 2 * S.lo + 1;
  constexpr int o1 = (S.l1 == 0) ? 0 : ((S.l1 == 1) ? 1 : 4);
  constexpr int o2 = (S.l2 == 0) ? 0 : ((S.l2 == 1) ? 1 : 4);
  constexpr int flat = S.off + (ia * d2 + ib) * d3 + cc;
  p[cc] = fmaf(w.v[flat], a[o1 + ia] * b[o2 + ib], p[cc]);
}

template <int K, size_t... Es>
__device__ __forceinline__ void tp_sk_impl(const W3JPack& w, const float* __restrict__ tpw,
                                           int u, const float (&a)[9], const float (&b)[9],
                                           float (&o)[9], std::index_sequence<Es...>) {
  float p[5] = {0.f, 0.f, 0.f, 0.f, 0.f};
  (tp_se<K, (int)Es>(w, a, b, p), ...);
  constexpr SpIns S = SPT[K];
  constexpr int d3 = 2 * S.lo + 1;
  constexpr int o3 = (S.lo == 0) ? 0 : ((S.lo == 1) ? 1 : 4);
  const float wk = tpw[(int)S.kidx * 128 + u];
#pragma unroll
  for (int c = 0; c < d3; ++c) o[o3 + c] = fmaf(wk, p[c], o[o3 + c]);
}

template <int K>
__device__ __forceinline__ void tp_sk(const W3JPack& w, const float* __restrict__ tpw,
                                      int u, const float (&a)[9], const float (&b)[9],
                                      float (&o)[9]) {
  tp_sk_impl<K>(w, tpw, u, a, b, o, std::make_index_sequence<(size_t)SPT[K].n>{});
}

__global__ __launch_bounds__(256) void tp_sparse_kernel(const bf16* __restrict__ xl,
                                                        const bf16* __restrict__ xr,
                                                        const float* __restrict__ tpw,
                                                        bf16* __restrict__ xtp,
                                                        bf16* __restrict__ f0,
                                                        const W3JPack w3j) {
  const int idx = blockIdx.x * 256 + threadIdx.x;
  const int n = idx >> 7, u = idx & 127;
  const bf16* ap = xl + (size_t)n * DDIM + u;
  const bf16* bp = xr + (size_t)n * DDIM + u;
  float a[9], b[9], o[9];
#pragma unroll
  for (int c = 0; c < 9; ++c) {
    a[c] = (float)ap[c * 128];
    b[c] = (float)bp[c * 128];
    o[c] = 0.f;
  }
  tp_sk<0>(w3j, tpw, u, a, b, o);
  tp_sk<1>(w3j, tpw, u, a, b, o);
  tp_sk<2>(w3j, tpw, u, a, b, o);
  tp_sk<3>(w3j, tpw, u, a, b, o);
  tp_sk<4>(w3j, tpw, u, a, b, o);
  tp_sk<5>(w3j, tpw, u, a, b, o);
  tp_sk<6>(w3j, tpw, u, a, b, o);
  tp_sk<7>(w3j, tpw, u, a, b, o);
  tp_sk<8>(w3j, tpw, u, a, b, o);
  tp_sk<9>(w3j, tpw, u, a, b, o);
  tp_sk<10>(w3j, tpw, u, a, b, o);
  tp_sk<11>(w3j, tpw, u, a, b, o);
  tp_sk<12>(w3j, tpw, u, a, b, o);
  tp_sk<13>(w3j, tpw, u, a, b, o);
  tp_sk<14>(w3j, tpw, u, a, b, o);
  tp_epilogue(o, n, u, xtp, f0);
}

// ===================== launch =====================
extern "C" void kernel_launch(void* const* d_in, const int* in_sizes, int n_in,
                              void* d_out, int out_size, void* d_ws, size_t ws_size,
                              hipStream_t stream) {
  (void)in_sizes; (void)n_in; (void)out_size; (void)ws_size;
  if (!g_w3j_ready) return;
  ensure_w3j();
  const float* x      = (const float*)d_in[0];
  const float* oldfii = (const float*)d_in[1];
  const float* gl_w1  = (const float*)d_in[2];
  const float* gl_b1  = (const float*)d_in[3];
  const float* gl_w2  = (const float*)d_in[4];
  const float* gl_b2  = (const float*)d_in[5];
  const float* gr_w1  = (const float*)d_in[6];
  const float* gr_b1  = (const float*)d_in[7];
  const float* gr_w2  = (const float*)d_in[8];
  const float* gr_b2  = (const float*)d_in[9];
  const float* gp_w1  = (const float*)d_in[10];
  const float* gp_b1  = (const float*)d_in[11];
  const float* gp_w2  = (const float*)d_in[12];
  const float* gp_b2  = (const float*)d_in[13];
  const float* Wl     = (const float*)d_in[14];
  const float* bl     = (const float*)d_in[15];
  const float* Wr     = (const float*)d_in[16];
  const float* br     = (const float*)d_in[17];
  const float* Wp     = (const float*)d_in[18];
  const float* tpw    = (const float*)d_in[19];
  float* out = (float*)d_out;
  char* base = (char*)d_ws;

  // ws layout (324 MiB peak):
  const size_t MiB = 1024 * 1024;
  bf16* wb   = (bf16*)base;                 // [0, 4)     converted weights
  bf16* f0bf = (bf16*)(base + 4 * MiB);     // [4, 28)    f0 bf16
  bf16* hbf  = (bf16*)(base + 28 * MiB);    // [28, 76)   gate hidden l+r bf16
  bf16* gbf  = (bf16*)(base + 76 * MiB);    // [76, 124)  gate out l+r bf16
  bf16* xT   = (bf16*)(base + 124 * MiB);   // [124, 188) x compact bf16
  bf16* xl   = (bf16*)(base + 188 * MiB);   // [188, 260) xl bf16
  bf16* xtp  = (bf16*)(base + 260 * MiB);   // [260, 324) xtp compact bf16
  bf16* xr   = (bf16*)d_out;                // xr bf16 in d_out (dead before final writes)

  const size_t NH = (size_t)NND * HDIM;
  const bf16* w_g1l = wb;
  const bf16* w_g2l = wb + 1 * 147456;
  const bf16* w_g1r = wb + 2 * 147456;
  const bf16* w_g2r = wb + 3 * 147456;
  const bf16* w_g1p = wb + 4 * 147456;
  const bf16* w_g2p = wb + 5 * 147456;
  const bf16* w_l   = wb + WB_O3_OFF;
  const bf16* w_r   = wb + WB_O3_OFF + 1 * 49152;
  const bf16* w_p   = wb + WB_O3_OFF + 2 * 49152;

  WPtrs wp;
  wp.gw[0] = gl_w1; wp.gw[1] = gl_w2; wp.gw[2] = gr_w1; wp.gw[3] = gr_w2;
  wp.gw[4] = gp_w1; wp.gw[5] = gp_w2;
  wp.ow[0] = Wl; wp.ow[1] = Wr; wp.ow[2] = Wp;

  dim3 b256(256);
  const int nb_nu = NND * 128 / 256;  // 16384
  DualPtrs d0 = {};

  // fused prologue: f0/xT build + weight prep (independent halves, one dispatch)
  prep_f0x_kernel<<<16384 + 5184, b256, 0, stream>>>(wp, wb, x, f0bf, xT);

  // gates l+r merged (64x128 tiles: 3 col-tiles per set)
  DualPtrs d_g1 = {f0bf, w_g1r, gr_b1, hbf + NH};
  mm_kernel<0, 3, true><<<dim3(512, 6), b256, 0, stream>>>(f0bf, w_g1l, gl_b1, hbf, d_g1);
  DualPtrs d_g2 = {hbf + NH, w_g2r, gr_b2, gbf + NH};
  mm_kernel<1, 3, true><<<dim3(512, 6), b256, 0, stream>>>(hbf, w_g2l, gl_b2, gbf, d_g2);

  // o3 first stage l+r combined (64x128 tiles, XCD-swizzled)
  O3First of;
  of.xT = xT;
  of.g[0] = gbf;      of.g[1] = gbf + NH;
  of.w[0] = w_l;      of.w[1] = w_r;
  of.bias[0] = bl;    of.bias[1] = br;
  of.dst[0] = xl;     of.dst[1] = xr;
  o3_first_kernel<<<9216, b256, 0, stream>>>(of);

  // tensor product (+ fused product-gate f0)
  if (g_use_sparse)
    tp_sparse_kernel<<<nb_nu, b256, 0, stream>>>(xl, xr, tpw, xtp, f0bf, g_w3j);
  else
    tp_dense_kernel<<<nb_nu, b256, 0, stream>>>(xl, xr, tpw, xtp, f0bf, g_w3j);

  // product gate (two plain dispatches)
  mm_kernel<0, 3, false><<<dim3(512, 3), b256, 0, stream>>>(f0bf, w_g1p, gp_b1, hbf, d0);
  mm_kernel<1, 3, false><<<dim3(512, 3), b256, 0, stream>>>(hbf, w_g2p, gp_b2, gbf, d0);

  // final o3 combined (+ residual, 64x64 tiles, XCD-swizzled)
  O3Final of2;
  of2.xtp = xtp;
  of2.g = gbf;
  of2.w = w_p;
  of2.oldf = oldfii;
  of2.out = out;
  o3_final_kernel<<<9216, b256, 0, stream>>>(of2);
}

// Round 17
// 438.937 us; speedup vs baseline: 1.0366x; 1.0366x over previous
//
#include <hip/hip_runtime.h>
#include <cmath>
#include <complex>
#include <cstdint>
#include <cstdio>
#include <cstring>
#include <mutex>
#include <string>
#include <utility>
#include <vector>
#include <dlfcn.h>

#define NND 32768
#define DDIM 1152
#define HDIM 384

typedef __bf16 bf16;
typedef __attribute__((ext_vector_type(8))) __bf16 bf16x8;
typedef __attribute__((ext_vector_type(4))) float f32x4;

// ===================== host: Wigner 3j generation (fallback path) =====================
namespace w3jgen {
using cd = std::complex<double>;

static void real_gens(int l, std::vector<double>* R) {
  const int d = 2 * l + 1;
  std::vector<cd> Lp(d * d), Lm(d * d);
  for (int i = 0; i + 1 < d; ++i) {
    double m = double(i - l);
    Lp[(i + 1) * d + i] = cd(std::sqrt(double(l) * (l + 1) - m * (m + 1)), 0.0);
  }
  for (int i = 0; i < d; ++i)
    for (int j = 0; j < d; ++j) Lm[i * d + j] = std::conj(Lp[j * d + i]);
  std::vector<cd> X[3];
  for (int a = 0; a < 3; ++a) X[a].assign(d * d, cd(0, 0));
  for (int i = 0; i < d * d; ++i) {
    X[0][i] = (Lp[i] + Lm[i]) * 0.5;
    X[1][i] = (Lp[i] - Lm[i]) / cd(0.0, 2.0);
  }
  for (int i = 0; i < d; ++i) X[2][i * d + i] = cd(double(i - l), 0.0);
  std::vector<cd> U(d * d, cd(0, 0));
  const double s2 = std::sqrt(2.0);
  for (int m = -l; m <= l; ++m) {
    int i = m + l;
    double sgn = (std::abs(m) % 2) ? -1.0 : 1.0;
    if (m < 0) {
      U[i * d + (l + m)] = cd(0.0, 1.0 / s2);
      U[i * d + (l - m)] = cd(0.0, -sgn / s2);
    } else if (m == 0) {
      U[i * d + l] = cd(1.0, 0.0);
    } else {
      U[i * d + (l - m)] = cd(1.0 / s2, 0.0);
      U[i * d + (l + m)] = cd(sgn / s2, 0.0);
    }
  }
  for (int a = 0; a < 3; ++a) {
    std::vector<cd> T(d * d, cd(0, 0)), T2(d * d, cd(0, 0));
    for (int i = 0; i < d; ++i)
      for (int k = 0; k < d; ++k) {
        cd u = U[i * d + k];
        if (u == cd(0, 0)) continue;
        for (int j = 0; j < d; ++j) T[i * d + j] += u * (cd(0, -1) * X[a][k * d + j]);
      }
    for (int i = 0; i < d; ++i)
      for (int k = 0; k < d; ++k) {
        cd t = T[i * d + k];
        if (t == cd(0, 0)) continue;
        for (int j = 0; j < d; ++j) T2[i * d + j] += t * std::conj(U[j * d + k]);
      }
    R[a].resize(d * d);
    for (int i = 0; i < d * d; ++i) R[a][i] = T2[i].real();
  }
}

static void wigner3j(int l1, int l2, int l3, float* out) {
  std::vector<double> X1[3], X2[3], X3[3];
  real_gens(l1, X1);
  real_gens(l2, X2);
  real_gens(l3, X3);
  const int d1 = 2 * l1 + 1, d2 = 2 * l2 + 1, d3 = 2 * l3 + 1;
  const int K = d1 * d2 * d3;
  std::vector<double> M((size_t)3 * K * K, 0.0);
  for (int a = 0; a < 3; ++a) {
    double* Ma = &M[(size_t)a * K * K];
    for (int i = 0; i < d1; ++i)
      for (int j = 0; j < d1; ++j) {
        double v = X1[a][i * d1 + j];
        if (v == 0.0) continue;
        for (int k = 0; k < d2; ++k)
          for (int m = 0; m < d3; ++m)
            Ma[(size_t)((i * d2 + k) * d3 + m) * K + ((j * d2 + k) * d3 + m)] += v;
      }
    for (int k = 0; k < d2; ++k)
      for (int l = 0; l < d2; ++l) {
        double v = X2[a][k * d2 + l];
        if (v == 0.0) continue;
        for (int i = 0; i < d1; ++i)
          for (int m = 0; m < d3; ++m)
            Ma[(size_t)((i * d2 + k) * d3 + m) * K + ((i * d2 + l) * d3 + m)] += v;
      }
    for (int m = 0; m < d3; ++m)
      for (int n = 0; n < d3; ++n) {
        double v = X3[a][m * d3 + n];
        if (v == 0.0) continue;
        for (int i = 0; i < d1; ++i)
          for (int k = 0; k < d2; ++k)
            Ma[(size_t)((i * d2 + k) * d3 + m) * K + ((i * d2 + k) * d3 + n)] += v;
      }
  }
  const int rows = 3 * K;
  std::vector<int> pivrow(K, -1);
  int r = 0;
  for (int c = 0; c < K && r < rows; ++c) {
    int p = -1;
    double best = 1e-9;
    for (int q = r; q < rows; ++q) {
      double v = std::fabs(M[(size_t)q * K + c]);
      if (v > best) { best = v; p = q; }
    }
    if (p < 0) continue;
    if (p != r)
      for (int j = 0; j < K; ++j) std::swap(M[(size_t)p * K + j], M[(size_t)r * K + j]);
    double inv = 1.0 / M[(size_t)r * K + c];
    for (int j = 0; j < K; ++j) M[(size_t)r * K + j] *= inv;
    for (int q = 0; q < rows; ++q) {
      if (q == r) continue;
      double f = M[(size_t)q * K + c];
      if (f == 0.0) continue;
      for (int j = 0; j < K; ++j) M[(size_t)q * K + j] -= f * M[(size_t)r * K + j];
    }
    pivrow[c] = r;
    ++r;
  }
  int cf = -1;
  for (int c = 0; c < K; ++c)
    if (pivrow[c] < 0) { cf = c; break; }
  std::vector<double> v(K, 0.0);
  v[cf] = 1.0;
  for (int c = 0; c < K; ++c)
    if (pivrow[c] >= 0) v[c] = -M[(size_t)pivrow[c] * K + cf];
  double nrm = 0.0;
  for (double x : v) nrm += x * x;
  nrm = std::sqrt(nrm);
  for (double& x : v) x /= nrm;
  double mx = 0.0;
  for (double x : v) mx = std::max(mx, std::fabs(x));
  int idx = 0;
  for (int i = 0; i < K; ++i)
    if (std::fabs(v[i]) > mx - 1e-9) { idx = i; break; }
  double s = (v[idx] < 0 ? -1.0 : 1.0);
  for (int i = 0; i < K; ++i) out[i] = (float)(v[i] * s);
}
}  // namespace w3jgen

struct W3JPack { float v[615]; };
static W3JPack g_w3j;
static const bool g_w3j_ready = [] {
  const int L1[15] = {0, 0, 0, 1, 1, 1, 1, 1, 1, 2, 2, 2, 2, 2, 2};
  const int L2[15] = {0, 1, 2, 0, 1, 1, 1, 2, 2, 0, 1, 1, 2, 2, 2};
  const int LO[15] = {0, 1, 2, 1, 0, 1, 2, 1, 2, 2, 1, 2, 0, 1, 2};
  const int OFF[15] = {0, 1, 10, 35, 44, 53, 80, 125, 170, 245, 270, 315, 390, 415, 490};
  for (int k = 0; k < 15; ++k)
    w3jgen::wigner3j(L1[k], L2[k], LO[k], g_w3j.v + OFF[k]);
  return true;
}();

// ===================== sparse W3J structure =====================
struct SpEnt { signed char ia, ib, c; };
struct SpIns { signed char l1, l2, lo; short off; signed char kidx, n; SpEnt e[25]; };
constexpr SpIns SPT[15] = {
  {0,0,0,   0, 0, 1, {{0,0,0}}},
  {0,1,1,   1, 1, 3, {{0,0,0},{0,1,1},{0,2,2}}},
  {0,2,2,  10, 2, 5, {{0,0,0},{0,1,1},{0,2,2},{0,3,3},{0,4,4}}},
  {1,0,1,  35, 3, 3, {{0,0,0},{1,0,1},{2,0,2}}},
  {1,1,0,  44, 4, 3, {{0,0,0},{1,1,0},{2,2,0}}},
  {1,1,1,  53, 5, 6, {{0,1,2},{0,2,1},{1,0,2},{1,2,0},{2,0,1},{2,1,0}}},
  {1,1,2,  80, 6,11, {{0,0,2},{0,0,4},{1,1,2},{2,2,2},{2,2,4},{0,1,1},{1,0,1},{0,2,0},{2,0,0},{1,2,3},{2,1,3}}},
  {1,2,1, 125, 7,11, {{0,2,0},{0,4,0},{1,2,1},{2,2,2},{2,4,2},{0,1,1},{1,1,0},{0,0,2},{2,0,0},{1,3,2},{2,3,1}}},
  {1,2,2, 170, 8,16, {{0,0,1},{0,1,0},{0,2,3},{0,3,2},{0,3,4},{0,4,3},{1,0,4},{1,4,0},{1,1,3},{1,3,1},{2,1,2},{2,2,1},{2,1,4},{2,4,1},{2,0,3},{2,3,0}}},
  {2,0,2, 245, 9, 5, {{0,0,0},{1,0,1},{2,0,2},{3,0,3},{4,0,4}}},
  {2,1,1, 270,10,11, {{2,0,0},{4,0,0},{2,1,1},{2,2,2},{4,2,2},{1,0,1},{1,1,0},{0,0,2},{0,2,0},{3,1,2},{3,2,1}}},
  {2,1,2, 315,11,16, {{0,0,1},{1,0,0},{2,0,3},{3,0,2},{3,0,4},{4,0,3},{0,1,4},{4,1,0},{1,1,3},{3,1,1},{1,2,2},{2,2,1},{1,2,4},{4,2,1},{0,2,3},{3,2,0}}},
  {2,2,0, 390,12, 5, {{0,0,0},{1,1,0},{2,2,0},{3,3,0},{4,4,0}}},
  {2,2,1, 415,13,16, {{0,1,0},{1,0,0},{2,3,0},{3,2,0},{3,4,0},{4,3,0},{0,4,1},{4,0,1},{1,3,1},{3,1,1},{1,2,2},{2,1,2},{1,4,2},{4,1,2},{0,3,2},{3,0,2}}},
  {2,2,2, 490,14,25, {{2,2,2},{0,0,2},{0,2,0},{2,0,0},{1,1,2},{1,2,1},{2,1,1},{3,3,2},{3,2,3},{2,3,3},{4,4,2},{4,2,4},{2,4,4},{1,1,4},{1,4,1},{4,1,1},{3,3,4},{3,4,3},{4,3,3},{0,1,3},{0,3,1},{1,0,3},{1,3,0},{3,0,1},{3,1,0}}},
};

static bool validate_sparse() {
  bool mark[615] = {};
  for (int k = 0; k < 15; ++k) {
    const SpIns& S = SPT[k];
    const int d2 = 2 * S.l2 + 1, d3 = 2 * S.lo + 1;
    for (int e = 0; e < S.n; ++e) {
      int flat = S.off + (S.e[e].ia * d2 + S.e[e].ib) * d3 + S.e[e].c;
      if (flat < 0 || flat >= 615) return false;
      mark[flat] = true;
    }
  }
  for (int i = 0; i < 615; ++i)
    if (!mark[i] && std::fabs(g_w3j.v[i]) > 1e-4f) return false;
  return true;
}
static bool g_use_sparse = false;

// ===================== host: bit-exact W3J via in-process numpy =====================
static const char* kPySrc = R"PY(
def _sl7791_w3j(addr):
    import numpy as np, ctypes
    def _su2_gen(l):
        m = np.arange(-l, l + 1)
        Lz = np.diag(m).astype(complex)
        Lp = np.zeros((2 * l + 1, 2 * l + 1), complex)
        for i in range(2 * l):
            Lp[i + 1, i] = np.sqrt(l * (l + 1) - m[i] * (m[i] + 1))
        Lm = Lp.conj().T
        return ((Lp + Lm) / 2, (Lp - Lm) / 2j, Lz)
    def _c2r(l):
        d = 2 * l + 1
        U = np.zeros((d, d), complex)
        s2 = np.sqrt(2.0)
        for m in range(-l, l + 1):
            i = m + l
            if m < 0:
                U[i, l + m] = 1j / s2
                U[i, l - m] = -1j * (-1) ** m / s2
            elif m == 0:
                U[i, l] = 1.0
            else:
                U[i, l - m] = 1.0 / s2
                U[i, l + m] = (-1) ** m / s2
        return U
    def _real_gens(l):
        U = _c2r(l)
        return [np.real(U @ (-1j * L) @ U.conj().T) for L in _su2_gen(l)]
    def _w3j(l1, l2, l3):
        X1, X2, X3 = (_real_gens(l1), _real_gens(l2), _real_gens(l3))
        d1, d2, d3 = (2 * l1 + 1, 2 * l2 + 1, 2 * l3 + 1)
        I1, I2, I3 = (np.eye(d1), np.eye(d2), np.eye(d3))
        blocks = []
        for a in range(3):
            T = np.einsum('ij,kl,mn->ikmjln', X1[a], I2, I3) + np.einsum('ij,kl,mn->ikmjln', I1, X2[a], I3) + np.einsum('ij,kl,mn->ikmjln', I1, I2, X3[a])
            blocks.append(T.reshape(d1 * d2 * d3, d1 * d2 * d3))
        M = np.concatenate(blocks, 0)
        _, _, vh = np.linalg.svd(M)
        C = vh[-1].reshape(d1, d2, d3)
        if C.flat[np.argmax(np.abs(C))] < 0:
            C = -C
        return (C / np.linalg.norm(C)).astype(np.float32)
    INS = [(0,0,0),(0,1,1),(0,2,2),(1,0,1),(1,1,0),(1,1,1),(1,1,2),(1,2,1),(1,2,2),(2,0,2),(2,1,1),(2,1,2),(2,2,0),(2,2,1),(2,2,2)]
    flat = np.ascontiguousarray(np.concatenate([_w3j(*i).ravel() for i in INS]).astype(np.float32))
    ctypes.memmove(addr, flat.ctypes.data, flat.nbytes)
)PY";

static bool python_w3j() {
  typedef int (*PyIsInit_t)();
  typedef int (*PyGILEnsure_t)();
  typedef void (*PyGILRelease_t)(int);
  typedef int (*PyRunStr_t)(const char*);
  void* h = nullptr;  // RTLD_DEFAULT
  PyIsInit_t is_init = (PyIsInit_t)dlsym(h, "Py_IsInitialized");
  PyGILEnsure_t gil_ens = (PyGILEnsure_t)dlsym(h, "PyGILState_Ensure");
  PyGILRelease_t gil_rel = (PyGILRelease_t)dlsym(h, "PyGILState_Release");
  PyRunStr_t run = (PyRunStr_t)dlsym(h, "PyRun_SimpleString");
  if (!is_init || !gil_ens || !gil_rel || !run) return false;
  if (!is_init()) return false;
  std::string script(kPySrc);
  script += "\n_sl7791_w3j(" + std::to_string((unsigned long long)(uintptr_t)g_w3j.v) +
            ")\ndel _sl7791_w3j\n";
  int st = gil_ens();
  int rc = run(script.c_str());
  gil_rel(st);
  return rc == 0;
}

static std::once_flag g_w3j_once;
static void ensure_w3j() {
  std::call_once(g_w3j_once, [] {
    W3JPack backup = g_w3j;
    if (python_w3j()) {
      if (!(std::fabs(std::fabs(g_w3j.v[0]) - 1.0f) < 1e-3f)) g_w3j = backup;
    }
    g_use_sparse = validate_sparse();
  });
}

// ===================== device kernels =====================

struct WPtrs {
  const float* gw[6];
  const float* ow[3];
};
#define WB_O3_OFF 884736  // 6*147456

// ---- fused prologue: f0/xT build (blocks 0..16383) + weight prep (blocks 16384..21567) ----
__global__ __launch_bounds__(256) void prep_f0x_kernel(WPtrs p, bf16* __restrict__ wb,
                                                       const float* __restrict__ x,
                                                       bf16* __restrict__ f0,
                                                       bf16* __restrict__ xT) {
  const int bid = blockIdx.x;
  if (bid < 16384) {
    const int idx = bid * 256 + threadIdx.x;
    const int n = idx >> 7, u = idx & 127;
    const float* xr = x + (size_t)n * DDIM;
    const float x0 = xr[u];
    float v1[3], v2[5];
    float s1 = 0.f, s2 = 0.f;
#pragma unroll
    for (int i = 0; i < 3; ++i) { v1[i] = xr[128 + u * 3 + i]; s1 += v1[i] * v1[i]; }
#pragma unroll
    for (int i = 0; i < 5; ++i) { v2[i] = xr[512 + u * 5 + i]; s2 += v2[i] * v2[i]; }
    bf16* f = f0 + (size_t)n * HDIM;
    f[u] = (bf16)x0;
    f[128 + u] = (bf16)sqrtf(s1);
    f[256 + u] = (bf16)sqrtf(s2);
    bf16* xt = xT + (size_t)n * 1024;
#pragma unroll
    for (int i = 0; i < 3; ++i) xt[i * 128 + u] = (bf16)v1[i];
#pragma unroll
    for (int i = 0; i < 5; ++i) xt[(3 + i) * 128 + u] = (bf16)v2[i];
  } else {
    const int id = bid - 16384;
    const int y = id / 576;
    const int e = (id - y * 576) * 256 + threadIdx.x;
    if (y < 6) {
      wb[(size_t)y * 147456 + e] = (bf16)p.gw[y][e];
    } else {
      if (e >= 49152) return;
      const int j = y - 6;
      const int l = e >> 14, vu = e & 16383, v = vu >> 7, u = vu & 127;
      wb[WB_O3_OFF + (size_t)j * 49152 + l * 16384 + v * 128 + u] =
          (bf16)p.ow[j][l * 16384 + u * 128 + v];
    }
  }
}

// ---- gate GEMM (bf16 MFMA, 64x128 tile; optional dual set select on blockIdx.y) ----
struct DualPtrs { const void* A2; const bf16* W2; const float* bias2; void* D2; };

template <int EPI, int CB, bool DUAL>
__global__ __launch_bounds__(256) void mm_kernel(const void* Asrc, const bf16* Wt,
                                                 const float* bias, void* Dst, DualPtrs dp) {
  __shared__ alignas(16) bf16 As[64][72];
  __shared__ alignas(16) bf16 Bs[128][72];
  int by = blockIdx.y;
  if (DUAL && by >= CB) {
    by -= CB;
    Asrc = dp.A2; Wt = dp.W2; bias = dp.bias2; Dst = dp.D2;
  }
  const int t = threadIdx.x;
  const int row0 = blockIdx.x * 64;
  const int col0 = by * 128;
  const int wave = t >> 6, lane = t & 63;
  const int wm = wave >> 1, wn = wave & 1;
  const int lr = lane & 15, lk = (lane >> 4) * 8;
  f32x4 acc[2][4] = {};
  const int ra = t >> 2, cseg = (t & 3) * 16;
  const int rb = t >> 1, csegB = (t & 1) * 32;

  for (int k0 = 0; k0 < 384; k0 += 64) {
    const bf16* s = (const bf16*)Asrc + (size_t)(row0 + ra) * HDIM + k0 + cseg;
    bf16x8 a0 = *(const bf16x8*)s, a1 = *(const bf16x8*)(s + 8);
    const bf16* wsrc = Wt + (size_t)(col0 + rb) * HDIM + k0 + csegB;
    bf16x8 w0 = *(const bf16x8*)wsrc, w1 = *(const bf16x8*)(wsrc + 8);
    bf16x8 w2 = *(const bf16x8*)(wsrc + 16), w3 = *(const bf16x8*)(wsrc + 24);
    __syncthreads();
    *(bf16x8*)&As[ra][cseg] = a0; *(bf16x8*)&As[ra][cseg + 8] = a1;
    *(bf16x8*)&Bs[rb][csegB] = w0; *(bf16x8*)&Bs[rb][csegB + 8] = w1;
    *(bf16x8*)&Bs[rb][csegB + 16] = w2; *(bf16x8*)&Bs[rb][csegB + 24] = w3;
    __syncthreads();
#pragma unroll
    for (int ks = 0; ks < 2; ++ks) {
      bf16x8 af[2], bfv[4];
#pragma unroll
      for (int f = 0; f < 2; ++f)
        af[f] = *(const bf16x8*)&As[wm * 32 + f * 16 + lr][ks * 32 + lk];
#pragma unroll
      for (int f = 0; f < 4; ++f)
        bfv[f] = *(const bf16x8*)&Bs[wn * 64 + f * 16 + lr][ks * 32 + lk];
#pragma unroll
      for (int fm = 0; fm < 2; ++fm)
#pragma unroll
        for (int fn = 0; fn < 4; ++fn)
          acc[fm][fn] = __builtin_amdgcn_mfma_f32_16x16x32_bf16(af[fm], bfv[fn], acc[fm][fn], 0, 0, 0);
    }
  }

#pragma unroll
  for (int fm = 0; fm < 2; ++fm) {
#pragma unroll
    for (int fn = 0; fn < 4; ++fn) {
      const int col = col0 + wn * 64 + fn * 16 + lr;
#pragma unroll
      for (int r = 0; r < 4; ++r) {
        const int rowo = row0 + wm * 32 + fm * 16 + (lane >> 4) * 4 + r;
        float v = acc[fm][fn][r] + bias[col];
        if (EPI == 0) v = v / (1.f + __expf(-v));
        ((bf16*)Dst)[(size_t)rowo * HDIM + col] = (bf16)v;
      }
    }
  }
}

// ---- o3 GEMM body, 64 rows x 128 cols (used by o3_first) ----
template <int TL>
__device__ __forceinline__ void o3_body128(int row0, const bf16* __restrict__ A,
                                           const bf16* __restrict__ G,
                                           const bf16* __restrict__ Wt,
                                           const float* __restrict__ bias,
                                           void* __restrict__ Dst, char* smraw) {
  bf16 (*As)[72] = reinterpret_cast<bf16(*)[72]>(smraw);
  bf16 (*Bs)[72] = reinterpret_cast<bf16(*)[72]>(smraw + 64 * 72 * 2);
  const int t = threadIdx.x;
  const int wave = t >> 6, lane = t & 63;
  const int wm = wave >> 1, wn = wave & 1;
  const int lr = lane & 15, lk = (lane >> 4) * 8;
  f32x4 acc[2][4] = {};
  const int ra = t >> 2, cseg = (t & 3) * 16;
  const int rb = t >> 1, csegB = (t & 1) * 32;
  constexpr int goff = (TL == 3) ? 128 : 256;
  constexpr int coff = (TL == 3) ? 1 : ((TL == 5) ? 4 : 0);
  const int rowg = row0 + ra;
  const int n_a = rowg / TL, i_a = rowg % TL;

  for (int k0 = 0; k0 < 128; k0 += 64) {
    bf16 av[16];
    if (TL == 1) {
      const bf16* s = A + (size_t)rowg * HDIM + k0 + cseg;
      *(bf16x8*)&av[0] = *(const bf16x8*)s;
      *(bf16x8*)&av[8] = *(const bf16x8*)(s + 8);
    } else {
      const bf16* xs = A + (size_t)n_a * 1024 + (coff - 1 + i_a) * 128 + k0 + cseg;
      const bf16* gs = G + (size_t)n_a * HDIM + goff + k0 + cseg;
      bf16 xv[16], gv[16];
      *(bf16x8*)&xv[0] = *(const bf16x8*)xs;
      *(bf16x8*)&xv[8] = *(const bf16x8*)(xs + 8);
      *(bf16x8*)&gv[0] = *(const bf16x8*)gs;
      *(bf16x8*)&gv[8] = *(const bf16x8*)(gs + 8);
#pragma unroll
      for (int e = 0; e < 16; ++e) av[e] = (bf16)((float)xv[e] * (float)gv[e]);
    }
    const bf16* wsrc = Wt + (size_t)rb * 128 + k0 + csegB;
    bf16x8 w0 = *(const bf16x8*)wsrc, w1 = *(const bf16x8*)(wsrc + 8);
    bf16x8 w2 = *(const bf16x8*)(wsrc + 16), w3 = *(const bf16x8*)(wsrc + 24);
    __syncthreads();
    *(bf16x8*)&As[ra][cseg] = *(bf16x8*)&av[0];
    *(bf16x8*)&As[ra][cseg + 8] = *(bf16x8*)&av[8];
    *(bf16x8*)&Bs[rb][csegB] = w0; *(bf16x8*)&Bs[rb][csegB + 8] = w1;
    *(bf16x8*)&Bs[rb][csegB + 16] = w2; *(bf16x8*)&Bs[rb][csegB + 24] = w3;
    __syncthreads();
#pragma unroll
    for (int ks = 0; ks < 2; ++ks) {
      bf16x8 af[2], bfv[4];
#pragma unroll
      for (int f = 0; f < 2; ++f)
        af[f] = *(const bf16x8*)&As[wm * 32 + f * 16 + lr][ks * 32 + lk];
#pragma unroll
      for (int f = 0; f < 4; ++f)
        bfv[f] = *(const bf16x8*)&Bs[wn * 64 + f * 16 + lr][ks * 32 + lk];
#pragma unroll
      for (int fm = 0; fm < 2; ++fm)
#pragma unroll
        for (int fn = 0; fn < 4; ++fn)
          acc[fm][fn] = __builtin_amdgcn_mfma_f32_16x16x32_bf16(af[fm], bfv[fn], acc[fm][fn], 0, 0, 0);
    }
  }

  const float rs = 0.08838834764831843f;  // 1/sqrt(128)
#pragma unroll
  for (int fm = 0; fm < 2; ++fm) {
#pragma unroll
    for (int fn = 0; fn < 4; ++fn) {
      const int col = wn * 64 + fn * 16 + lr;
#pragma unroll
      for (int r = 0; r < 4; ++r) {
        const int rowo = row0 + wm * 32 + fm * 16 + (lane >> 4) * 4 + r;
        float v = acc[fm][fn][r] * rs;
        if (TL == 1) v += bias[col];
        const int n = rowo / TL, ii = rowo % TL;
        ((bf16*)Dst)[(size_t)n * DDIM + (coff + ii) * 128 + col] = (bf16)v;
      }
    }
  }
}

// ---- o3 GEMM body, 64 rows x 64 cols (used by o3_final; r8-proven) ----
template <int TL>
__device__ __forceinline__ void o3_body64(int row0, int col0, const bf16* __restrict__ A,
                                          const bf16* __restrict__ G,
                                          const bf16* __restrict__ Wt,
                                          const float* __restrict__ oldf,
                                          float* __restrict__ Dst, char* smraw) {
  bf16 (*As)[72] = reinterpret_cast<bf16(*)[72]>(smraw);
  bf16 (*Bs)[72] = reinterpret_cast<bf16(*)[72]>(smraw + 64 * 72 * 2);
  float (*Cs)[65] = reinterpret_cast<float(*)[65]>(smraw);
  const int t = threadIdx.x;
  const int wave = t >> 6, lane = t & 63;
  const int wm = wave >> 1, wn = wave & 1;
  const int lr = lane & 15, lk = (lane >> 4) * 8;
  f32x4 acc[2][2] = {};
  const int ra = t >> 2, cseg = (t & 3) * 16;
  constexpr int goff = (TL == 3) ? 128 : 256;
  constexpr int coff = (TL == 3) ? 1 : ((TL == 5) ? 4 : 0);
  constexpr int moff = (TL == 3) ? 128 : 512;
  const int rowg = row0 + ra;
  const int n_a = rowg / TL, i_a = rowg % TL;

  for (int k0 = 0; k0 < 128; k0 += 64) {
    bf16 av[16];
    if (TL == 1) {
      const bf16* s = A + (size_t)rowg * HDIM + k0 + cseg;
      *(bf16x8*)&av[0] = *(const bf16x8*)s;
      *(bf16x8*)&av[8] = *(const bf16x8*)(s + 8);
    } else {
      const bf16* xs = A + (size_t)n_a * 1024 + (coff - 1 + i_a) * 128 + k0 + cseg;
      const bf16* gs = G + (size_t)n_a * HDIM + goff + k0 + cseg;
      bf16 xv[16], gv[16];
      *(bf16x8*)&xv[0] = *(const bf16x8*)xs;
      *(bf16x8*)&xv[8] = *(const bf16x8*)(xs + 8);
      *(bf16x8*)&gv[0] = *(const bf16x8*)gs;
      *(bf16x8*)&gv[8] = *(const bf16x8*)(gs + 8);
#pragma unroll
      for (int e = 0; e < 16; ++e) av[e] = (bf16)((float)xv[e] * (float)gv[e]);
    }
    const bf16* wsrc = Wt + (size_t)(col0 + ra) * 128 + k0 + cseg;
    bf16x8 w0 = *(const bf16x8*)wsrc;
    bf16x8 w1 = *(const bf16x8*)(wsrc + 8);
    __syncthreads();
    *(bf16x8*)&As[ra][cseg] = *(bf16x8*)&av[0];
    *(bf16x8*)&As[ra][cseg + 8] = *(bf16x8*)&av[8];
    *(bf16x8*)&Bs[ra][cseg] = w0;
    *(bf16x8*)&Bs[ra][cseg + 8] = w1;
    __syncthreads();
#pragma unroll
    for (int ks = 0; ks < 2; ++ks) {
      bf16x8 af[2], bfv[2];
#pragma unroll
      for (int f = 0; f < 2; ++f) {
        af[f]  = *(const bf16x8*)&As[wm * 32 + f * 16 + lr][ks * 32 + lk];
        bfv[f] = *(const bf16x8*)&Bs[wn * 32 + f * 16 + lr][ks * 32 + lk];
      }
#pragma unroll
      for (int fm = 0; fm < 2; ++fm)
#pragma unroll
        for (int fn = 0; fn < 2; ++fn)
          acc[fm][fn] = __builtin_amdgcn_mfma_f32_16x16x32_bf16(af[fm], bfv[fn], acc[fm][fn], 0, 0, 0);
    }
  }

  const float rs = 0.08838834764831843f;  // 1/sqrt(128)

  if (TL != 1) {  // LDS transpose, merged f32 + oldf
    __syncthreads();
#pragma unroll
    for (int fm = 0; fm < 2; ++fm)
#pragma unroll
      for (int fn = 0; fn < 2; ++fn)
#pragma unroll
        for (int r = 0; r < 4; ++r)
          Cs[wm * 32 + fm * 16 + (lane >> 4) * 4 + r][wn * 32 + fn * 16 + lr] =
              acc[fm][fn][r] * rs;
    __syncthreads();
    const int n_first = row0 / TL;
    const int n_last = (row0 + 63) / TL;
    for (int n = n_first; n <= n_last; ++n) {
      const size_t obase = (size_t)n * DDIM + moff + (size_t)col0 * TL;
      for (int e = t; e < 64 * TL; e += 256) {
        const int cl = e / TL;
        const int i = e - cl * TL;
        const int trow = n * TL + i - row0;
        if ((unsigned)trow < 64u) {
          const size_t oidx = obase + e;
          Dst[oidx] = Cs[trow][cl] + oldf[oidx];
        }
      }
    }
    return;
  }

#pragma unroll
  for (int fm = 0; fm < 2; ++fm) {
#pragma unroll
    for (int fn = 0; fn < 2; ++fn) {
      const int col = col0 + wn * 32 + fn * 16 + lr;
#pragma unroll
      for (int r = 0; r < 4; ++r) {
        const int rowo = row0 + wm * 32 + fm * 16 + (lane >> 4) * 4 + r;
        const size_t oidx = (size_t)rowo * DDIM + col;
        Dst[oidx] = acc[fm][fn][r] * rs + oldf[oidx];
      }
    }
  }
}

// ---- combined first-stage o3 (l+r): 9216 blocks, 64x128 tiles (TL5 first) ----
struct O3First {
  const bf16* xT;
  const bf16* g[2];
  const bf16* w[2];
  const float* bias[2];
  bf16* dst[2];
};
__global__ __launch_bounds__(256) void o3_first_kernel(O3First a) {
  __shared__ alignas(16) char smraw[27648];
  const int id = blockIdx.x;
  if (id < 5120) {
    const int set = id & 1, rt = id >> 1;
    o3_body128<5>(rt * 64, a.xT, a.g[set], a.w[set] + 32768, nullptr, a.dst[set], smraw);
  } else if (id < 8192) {
    const int tt = id - 5120;
    const int set = tt & 1, rt = tt >> 1;
    o3_body128<3>(rt * 64, a.xT, a.g[set], a.w[set] + 16384, nullptr, a.dst[set], smraw);
  } else {
    const int tt = id - 8192;
    const int set = tt & 1, rt = tt >> 1;
    o3_body128<1>(rt * 64, a.g[set], nullptr, a.w[set], a.bias[set], a.dst[set], smraw);
  }
}

// ---- combined final o3: 9216 blocks, 64x64 tiles (r8-proven) ----
struct O3Final {
  const bf16* xtp;
  const bf16* g;
  const bf16* w;
  const float* oldf;
  float* out;
};
__global__ __launch_bounds__(256) void o3_final_kernel(O3Final a) {
  __shared__ alignas(16) char smraw[18432];
  const int id = blockIdx.x;
  if (id < 1024) {
    const int col = id & 1, rt = id >> 1;
    o3_body64<1>(rt * 64, col * 64, a.g, nullptr, a.w, a.oldf, a.out, smraw);
  } else if (id < 4096) {
    const int tt = id - 1024;
    const int col = tt & 1, rt = tt >> 1;
    o3_body64<3>(rt * 64, col * 64, a.xtp, a.g, a.w + 16384, a.oldf, a.out, smraw);
  } else {
    const int tt = id - 4096;
    const int col = tt & 1, rt = tt >> 1;
    o3_body64<5>(rt * 64, col * 64, a.xtp, a.g, a.w + 32768, a.oldf, a.out, smraw);
  }
}

// ---- tensor product ----
__device__ __forceinline__ void tp_epilogue(float (&o)[9], int n, int u,
                                            bf16* __restrict__ xtp,
                                            bf16* __restrict__ f0) {
  const float s0 = 0.5773502691896258f;
  const float s1 = 0.7071067811865476f;
  const float s2 = 0.9128709291752769f;
  o[0] *= s0;
  o[1] *= s1; o[2] *= s1; o[3] *= s1;
  o[4] *= s2; o[5] *= s2; o[6] *= s2; o[7] *= s2; o[8] *= s2;
  const float n1 = sqrtf(o[1] * o[1] + o[2] * o[2] + o[3] * o[3]);
  const float n2 = sqrtf(o[4] * o[4] + o[5] * o[5] + o[6] * o[6] + o[7] * o[7] + o[8] * o[8]);
  bf16* f = f0 + (size_t)n * HDIM;
  f[u] = (bf16)o[0];
  f[128 + u] = (bf16)n1;
  f[256 + u] = (bf16)n2;
  bf16* op = xtp + (size_t)n * 1024 + u;
#pragma unroll
  for (int c = 1; c < 9; ++c) op[(c - 1) * 128] = (bf16)o[c];
}

template <int l1, int l2, int lo, int off, int kidx>
__device__ __forceinline__ void tp_one(const W3JPack& w3j, const float* __restrict__ tpw,
                                       int u, const float (&a)[9], const float (&b)[9],
                                       float (&o)[9]) {
  constexpr int d1 = 2 * l1 + 1, d2 = 2 * l2 + 1, d3 = 2 * lo + 1;
  constexpr int o1 = (l1 == 0) ? 0 : ((l1 == 1) ? 1 : 4);
  constexpr int o2 = (l2 == 0) ? 0 : ((l2 == 1) ? 1 : 4);
  constexpr int o3 = (lo == 0) ? 0 : ((lo == 1) ? 1 : 4);
  const float w = tpw[kidx * 128 + u];
  float ab[d1 * d2];
#pragma unroll
  for (int ia = 0; ia < d1; ++ia)
#pragma unroll
    for (int ib = 0; ib < d2; ++ib) ab[ia * d2 + ib] = a[o1 + ia] * b[o2 + ib];
#pragma unroll
  for (int c = 0; c < d3; ++c) {
    float p = 0.f;
#pragma unroll
    for (int e = 0; e < d1 * d2; ++e) p = fmaf(w3j.v[off + e * d3 + c], ab[e], p);
    o[o3 + c] = fmaf(w, p, o[o3 + c]);
  }
}

__global__ __launch_bounds__(256) void tp_dense_kernel(const bf16* __restrict__ xl,
                                                       const bf16* __restrict__ xr,
                                                       const float* __restrict__ tpw,
                                                       bf16* __restrict__ xtp,
                                                       bf16* __restrict__ f0,
                                                       const W3JPack w3j) {
  const int idx = blockIdx.x * 256 + threadIdx.x;
  const int n = idx >> 7, u = idx & 127;
  const bf16* ap = xl + (size_t)n * DDIM + u;
  const bf16* bp = xr + (size_t)n * DDIM + u;
  float a[9], b[9], o[9];
#pragma unroll
  for (int c = 0; c < 9; ++c) {
    a[c] = (float)ap[c * 128];
    b[c] = (float)bp[c * 128];
    o[c] = 0.f;
  }
  tp_one<0, 0, 0,   0,  0>(w3j, tpw, u, a, b, o);
  tp_one<0, 1, 1,   1,  1>(w3j, tpw, u, a, b, o);
  tp_one<0, 2, 2,  10,  2>(w3j, tpw, u, a, b, o);
  tp_one<1, 0, 1,  35,  3>(w3j, tpw, u, a, b, o);
  tp_one<1, 1, 0,  44,  4>(w3j, tpw, u, a, b, o);
  tp_one<1, 1, 1,  53,  5>(w3j, tpw, u, a, b, o);
  tp_one<1, 1, 2,  80,  6>(w3j, tpw, u, a, b, o);
  tp_one<1, 2, 1, 125,  7>(w3j, tpw, u, a, b, o);
  tp_one<1, 2, 2, 170,  8>(w3j, tpw, u, a, b, o);
  tp_one<2, 0, 2, 245,  9>(w3j, tpw, u, a, b, o);
  tp_one<2, 1, 1, 270, 10>(w3j, tpw, u, a, b, o);
  tp_one<2, 1, 2, 315, 11>(w3j, tpw, u, a, b, o);
  tp_one<2, 2, 0, 390, 12>(w3j, tpw, u, a, b, o);
  tp_one<2, 2, 1, 415, 13>(w3j, tpw, u, a, b, o);
  tp_one<2, 2, 2, 490, 14>(w3j, tpw, u, a, b, o);
  tp_epilogue(o, n, u, xtp, f0);
}

template <int K, int E>
__device__ __forceinline__ void tp_se(const W3JPack& w, const float (&a)[9],
                                      const float (&b)[9], float (&p)[5]) {
  constexpr SpIns S = SPT[K];
  constexpr int ia = S.e[E].ia, ib = S.e[E].ib, cc = S.e[E].c;
  constexpr int d2 = 2 * S.l2 + 1, d3 = 2 * S.lo + 1;
  constexpr int o1 = (S.l1 == 0) ? 0 : ((S.l1 == 1) ? 1 : 4);
  constexpr int o2 = (S.l2 == 0) ? 0 : ((S.l2 == 1) ? 1 : 4);
  constexpr int flat = S.off + (ia * d2 + ib) * d3 + cc;
  p[cc] = fmaf(w.v[flat], a[o1 + ia] * b[o2 + ib], p[cc]);
}

template <int K, size_t... Es>
__device__ __forceinline__ void tp_sk_impl(const W3JPack& w, const float* __restrict__ tpw,
                                           int u, const float (&a)[9], const float (&b)[9],
                                           float (&o)[9], std::index_sequence<Es...>) {
  float p[5] = {0.f, 0.f, 0.f, 0.f, 0.f};
  (tp_se<K, (int)Es>(w, a, b, p), ...);
  constexpr SpIns S = SPT[K];
  constexpr int d3 = 2 * S.lo + 1;
  constexpr int o3 = (S.lo == 0) ? 0 : ((S.lo == 1) ? 1 : 4);
  const float wk = tpw[(int)S.kidx * 128 + u];
#pragma unroll
  for (int c = 0; c < d3; ++c) o[o3 + c] = fmaf(wk, p[c], o[o3 + c]);
}

template <int K>
__device__ __forceinline__ void tp_sk(const W3JPack& w, const float* __restrict__ tpw,
                                      int u, const float (&a)[9], const float (&b)[9],
                                      float (&o)[9]) {
  tp_sk_impl<K>(w, tpw, u, a, b, o, std::make_index_sequence<(size_t)SPT[K].n>{});
}

__global__ __launch_bounds__(256) void tp_sparse_kernel(const bf16* __restrict__ xl,
                                                        const bf16* __restrict__ xr,
                                                        const float* __restrict__ tpw,
                                                        bf16* __restrict__ xtp,
                                                        bf16* __restrict__ f0,
                                                        const W3JPack w3j) {
  const int idx = blockIdx.x * 256 + threadIdx.x;
  const int n = idx >> 7, u = idx & 127;
  const bf16* ap = xl + (size_t)n * DDIM + u;
  const bf16* bp = xr + (size_t)n * DDIM + u;
  float a[9], b[9], o[9];
#pragma unroll
  for (int c = 0; c < 9; ++c) {
    a[c] = (float)ap[c * 128];
    b[c] = (float)bp[c * 128];
    o[c] = 0.f;
  }
  tp_sk<0>(w3j, tpw, u, a, b, o);
  tp_sk<1>(w3j, tpw, u, a, b, o);
  tp_sk<2>(w3j, tpw, u, a, b, o);
  tp_sk<3>(w3j, tpw, u, a, b, o);
  tp_sk<4>(w3j, tpw, u, a, b, o);
  tp_sk<5>(w3j, tpw, u, a, b, o);
  tp_sk<6>(w3j, tpw, u, a, b, o);
  tp_sk<7>(w3j, tpw, u, a, b, o);
  tp_sk<8>(w3j, tpw, u, a, b, o);
  tp_sk<9>(w3j, tpw, u, a, b, o);
  tp_sk<10>(w3j, tpw, u, a, b, o);
  tp_sk<11>(w3j, tpw, u, a, b, o);
  tp_sk<12>(w3j, tpw, u, a, b, o);
  tp_sk<13>(w3j, tpw, u, a, b, o);
  tp_sk<14>(w3j, tpw, u, a, b, o);
  tp_epilogue(o, n, u, xtp, f0);
}

// ===================== launch =====================
extern "C" void kernel_launch(void* const* d_in, const int* in_sizes, int n_in,
                              void* d_out, int out_size, void* d_ws, size_t ws_size,
                              hipStream_t stream) {
  (void)in_sizes; (void)n_in; (void)out_size; (void)ws_size;
  if (!g_w3j_ready) return;
  ensure_w3j();
  const float* x      = (const float*)d_in[0];
  const float* oldfii = (const float*)d_in[1];
  const float* gl_w1  = (const float*)d_in[2];
  const float* gl_b1  = (const float*)d_in[3];
  const float* gl_w2  = (const float*)d_in[4];
  const float* gl_b2  = (const float*)d_in[5];
  const float* gr_w1  = (const float*)d_in[6];
  const float* gr_b1  = (const float*)d_in[7];
  const float* gr_w2  = (const float*)d_in[8];
  const float* gr_b2  = (const float*)d_in[9];
  const float* gp_w1  = (const float*)d_in[10];
  const float* gp_b1  = (const float*)d_in[11];
  const float* gp_w2  = (const float*)d_in[12];
  const float* gp_b2  = (const float*)d_in[13];
  const float* Wl     = (const float*)d_in[14];
  const float* bl     = (const float*)d_in[15];
  const float* Wr     = (const float*)d_in[16];
  const float* br     = (const float*)d_in[17];
  const float* Wp     = (const float*)d_in[18];
  const float* tpw    = (const float*)d_in[19];
  float* out = (float*)d_out;
  char* base = (char*)d_ws;

  // ws layout (324 MiB peak):
  const size_t MiB = 1024 * 1024;
  bf16* wb   = (bf16*)base;                 // [0, 4)     converted weights
  bf16* f0bf = (bf16*)(base + 4 * MiB);     // [4, 28)    f0 bf16
  bf16* hbf  = (bf16*)(base + 28 * MiB);    // [28, 76)   gate hidden l+r bf16
  bf16* gbf  = (bf16*)(base + 76 * MiB);    // [76, 124)  gate out l+r bf16
  bf16* xT   = (bf16*)(base + 124 * MiB);   // [124, 188) x compact bf16
  bf16* xl   = (bf16*)(base + 188 * MiB);   // [188, 260) xl bf16
  bf16* xtp  = (bf16*)(base + 260 * MiB);   // [260, 324) xtp compact bf16
  bf16* xr   = (bf16*)d_out;                // xr bf16 in d_out (dead before final writes)

  const size_t NH = (size_t)NND * HDIM;
  const bf16* w_g1l = wb;
  const bf16* w_g2l = wb + 1 * 147456;
  const bf16* w_g1r = wb + 2 * 147456;
  const bf16* w_g2r = wb + 3 * 147456;
  const bf16* w_g1p = wb + 4 * 147456;
  const bf16* w_g2p = wb + 5 * 147456;
  const bf16* w_l   = wb + WB_O3_OFF;
  const bf16* w_r   = wb + WB_O3_OFF + 1 * 49152;
  const bf16* w_p   = wb + WB_O3_OFF + 2 * 49152;

  WPtrs wp;
  wp.gw[0] = gl_w1; wp.gw[1] = gl_w2; wp.gw[2] = gr_w1; wp.gw[3] = gr_w2;
  wp.gw[4] = gp_w1; wp.gw[5] = gp_w2;
  wp.ow[0] = Wl; wp.ow[1] = Wr; wp.ow[2] = Wp;

  dim3 b256(256);
  const int nb_nu = NND * 128 / 256;  // 16384
  DualPtrs d0 = {};

  // fused prologue: f0/xT build + weight prep (independent halves, one dispatch)
  prep_f0x_kernel<<<16384 + 5184, b256, 0, stream>>>(wp, wb, x, f0bf, xT);

  // gates l+r merged (64x128 tiles: 3 col-tiles per set)
  DualPtrs d_g1 = {f0bf, w_g1r, gr_b1, hbf + NH};
  mm_kernel<0, 3, true><<<dim3(512, 6), b256, 0, stream>>>(f0bf, w_g1l, gl_b1, hbf, d_g1);
  DualPtrs d_g2 = {hbf + NH, w_g2r, gr_b2, gbf + NH};
  mm_kernel<1, 3, true><<<dim3(512, 6), b256, 0, stream>>>(hbf, w_g2l, gl_b2, gbf, d_g2);

  // o3 first stage l+r combined (64x128 tiles)
  O3First of;
  of.xT = xT;
  of.g[0] = gbf;      of.g[1] = gbf + NH;
  of.w[0] = w_l;      of.w[1] = w_r;
  of.bias[0] = bl;    of.bias[1] = br;
  of.dst[0] = xl;     of.dst[1] = xr;
  o3_first_kernel<<<9216, b256, 0, stream>>>(of);

  // tensor product (+ fused product-gate f0)
  if (g_use_sparse)
    tp_sparse_kernel<<<nb_nu, b256, 0, stream>>>(xl, xr, tpw, xtp, f0bf, g_w3j);
  else
    tp_dense_kernel<<<nb_nu, b256, 0, stream>>>(xl, xr, tpw, xtp, f0bf, g_w3j);

  // product gate (two plain dispatches)
  mm_kernel<0, 3, false><<<dim3(512, 3), b256, 0, stream>>>(f0bf, w_g1p, gp_b1, hbf, d0);
  mm_kernel<1, 3, false><<<dim3(512, 3), b256, 0, stream>>>(hbf, w_g2p, gp_b2, gbf, d0);

  // final o3 combined (+ residual, 64x64 tiles — r8-proven)
  O3Final of2;
  of2.xtp = xtp;
  of2.g = gbf;
  of2.w = w_p;
  of2.oldf = oldfii;
  of2.out = out;
  o3_final_kernel<<<9216, b256, 0, stream>>>(of2);
}